// Round 4
// baseline (168.495 us; speedup 1.0000x reference)
//
#include <hip/hip_runtime.h>

// MultiLIF forward: B=32, L=2048, K=512. One thread per (b,k); 256 waves total
// (1 wave/CU — structural). Numerics: IEEE f32 div replaced by provably
// identical f64-multiply rounding (x/20 == (float)((double)x*0.05) for all f32
// x; quotient never a 24-bit rounding midpoint, margin ~2^-28 vs f64 error
// ~2^-52.5); no fma contraction; spike select/reset exact. absmax == 0.
//
// R4: attack the VMEM in-order-retire stall (vmcnt is 6-bit, retires in issue
// order; the wave self-throttles at 63 outstanding and then every VMEM issue
// waits at head-of-line retire rate).
//  - Drop nontemporal stores: nt plausibly acks at HBM (~1000cy); plain stores
//    ack at L2 (~200-300cy) -> 3-5x faster queue drain.
//  - Per sub-block order: prefetch loads FIRST, compute to registers, stores
//    LAST -> waited-on loads are never queued behind same-block stores.

#define LL 2048
#define KK 512

constexpr int U = 8;   // steps per sub-block
constexpr int NB = 4;  // rotating prefetch buffers (distance (NB-1)*U = 24 steps)

__global__ __launch_bounds__(64, 1) void lif_kernel(const float* __restrict__ I,
                                                    float* __restrict__ spikes,
                                                    float* __restrict__ series) {
#pragma clang fp contract(off)
    const int e = blockIdx.x * 64 + threadIdx.x;   // 0..16383 = b*512 + k
    const int b = e >> 9;
    const int k = e & 511;
    const size_t base = (size_t)b * LL * KK + k;
    const float* Ip = I + base;
    float* sp = spikes + base;
    float* ss = series + base;

    float v = 0.0f, a = 0.0f, n = 0.0f;

    float q[NB][U];  // all indices compile-time after unrolling
    // prologue: sub-blocks 0..NB-2 into buffers 0..NB-2
#pragma unroll
    for (int st = 0; st < NB - 1; ++st)
#pragma unroll
        for (int u = 0; u < U; ++u)
            q[st][u] = Ip[(size_t)(st * U + u) * KK];

    for (int t0 = 0; t0 < LL; t0 += NB * U) {
#pragma unroll
        for (int st = 0; st < NB; ++st) {
            const int tb = t0 + st * U;

            // (1) prefetch loads first: time tb + 24 into the buffer freed
            //     last sub-block ((st+NB-1)%NB). Loads precede this block's
            //     stores in vmcnt issue order.
            const int tp = tb + (NB - 1) * U;
            const int pb = (st + NB - 1) % NB;
            if (tp < LL) {
#pragma unroll
                for (int u = 0; u < U; ++u)
                    q[pb][u] = Ip[(size_t)(tp + u) * KK];
            }

            // (2) compute 8 steps into register buffers (no VMEM on the chain)
            float sb[U], nb_[U];
#pragma unroll
            for (int u = 0; u < U; ++u) {
                const float It = q[st][u];
                // v = (v - v/TAU) + I_t ; v/20 via exact f64-mul rounding
                v = v - (float)((double)v * 0.05) + It;
                const float th = 1.0f + 1.5f * a;   // mul then add, no fma
                const bool fired = (v >= th);
                const float s1 = fired ? 1.0f : 0.0f;
                n = n + s1;                         // cumulative count (exact)
                v = fired ? -0.5f : v;              // exact select
                a = a - (float)((double)a * 0.01) + s1;
                sb[u] = s1;
                nb_[u] = n;
            }

            // (3) stores last, plain (L2-ack, not nontemporal)
#pragma unroll
            for (int u = 0; u < U; ++u) {
                sp[(size_t)(tb + u) * KK] = sb[u];
                ss[(size_t)(tb + u) * KK] = nb_[u];
            }
        }
    }
}

extern "C" void kernel_launch(void* const* d_in, const int* in_sizes, int n_in,
                              void* d_out, int out_size, void* d_ws, size_t ws_size,
                              hipStream_t stream) {
    const float* I = (const float*)d_in[0];
    float* spikes = (float*)d_out;
    float* series = (float*)d_out + (size_t)32 * LL * KK;
    lif_kernel<<<256, 64, 0, stream>>>(I, spikes, series);
}

// Round 5
// 166.135 us; speedup vs baseline: 1.0142x; 1.0142x over previous
//
#include <hip/hip_runtime.h>

// MultiLIF forward: B=32, L=2048, K=512.
// R5: split into (1) serial scan emitting packed spike bits + chunk-head
// counts (writes 268MB -> 8.4MB; the 2x256B/step store drain on 1 wave/CU was
// the ~84cyc/step stall), and (2) a massively parallel expansion kernel
// (16384 waves) that streams the 268MB of f32 outputs at full-occupancy BW.
// Packed words/bases live in d_out itself at each chunk's first row; kernel 2
// threads read only locations they themselves overwrite (per-lane column
// ownership -> no cross-thread hazard).
//
// Numerics (absmax must stay 0): x/20 and x/100 via split-constant fma:
// e=x*C_LO; d=fmaf(x,C_HI,e) -> single rounding of x*(C_HI+C_LO), total error
// ~2^-49 relative, while the exact quotient m/(5*2^k) (resp m/(25*2^k)) is
// provably >=~2^-30 relative from any f32 rounding midpoint (25*odd needs >24
// mantissa bits) -> result == IEEE division for ALL f32 x. th = 1 + 1.5*a
// kept as separate mul+add (contract off); select/reset exact; n is small-int
// exact in f32.

#define LL 2048
#define KK 512

constexpr int U = 8;    // steps per sub-block (kernel 1)
constexpr int NB = 4;   // rotating prefetch buffers; NB*U = 32 = chunk size
constexpr int CH = 32;  // steps per packed chunk
constexpr float C20_HI = 0.05f;
constexpr float C20_LO = (float)(0.05 - (double)C20_HI);
constexpr float C100_HI = 0.01f;
constexpr float C100_LO = (float)(0.01 - (double)C100_HI);

__global__ __launch_bounds__(64, 1) void lif_scan(const float* __restrict__ I,
                                                  float* __restrict__ spikes,
                                                  float* __restrict__ series) {
#pragma clang fp contract(off)
    const int e = blockIdx.x * 64 + threadIdx.x;   // b*512 + k
    const int b = e >> 9;
    const int k = e & 511;
    const size_t base = (size_t)b * LL * KK + k;
    const float* Ip = I + base;

    float v = 0.0f, a = 0.0f, n = 0.0f;

    float q[NB][U];
#pragma unroll
    for (int st = 0; st < NB; ++st)
#pragma unroll
        for (int u = 0; u < U; ++u)
            q[st][u] = Ip[(size_t)(st * U + u) * KK];

    for (int t0 = 0; t0 < LL; t0 += CH) {
        // chunk head: running count BEFORE this chunk
        series[base + (size_t)t0 * KK] = n;
        unsigned bits = 0;
#pragma unroll
        for (int st = 0; st < NB; ++st) {
            const int tb = t0 + st * U;
#pragma unroll
            for (int u = 0; u < U; ++u) {
                const float It = q[st][u];
                // v = (v - v/20) + I_t ; exact div via split-fma
                const float d1 = __builtin_fmaf(v, C20_HI, v * C20_LO);
                v = v - d1 + It;
                const float th = 1.0f + 1.5f * a;   // mul then add, no fma
                const bool fired = (v >= th);
                const float s1 = fired ? 1.0f : 0.0f;
                n = n + s1;
                v = fired ? -0.5f : v;              // exact reset select
                const float d2 = __builtin_fmaf(a, C100_HI, a * C100_LO);
                a = a - d2 + s1;
                bits |= (fired ? (1u << (st * U + u)) : 0u);
            }
            // prefetch the sub-block NB*U steps ahead into the buffer just used
            if (tb + NB * U < LL) {
#pragma unroll
                for (int u = 0; u < U; ++u)
                    q[st][u] = Ip[(size_t)(tb + NB * U + u) * KK];
            }
        }
        ((unsigned*)spikes)[base + (size_t)t0 * KK] = bits;
    }
}

__global__ __launch_bounds__(256) void lif_expand(float* __restrict__ spikes,
                                                  float* __restrict__ series) {
    const int gid = blockIdx.x * 256 + threadIdx.x;
    const int lane = gid & 63;
    const int w = gid >> 6;            // 0..16383 = ((b*64)+c)*8 + kg
    const int kg = w & 7;
    const int c = (w >> 3) & 63;
    const int b = w >> 9;
    const int k = kg * 64 + lane;
    const size_t addr0 = (size_t)b * LL * KK + (size_t)c * CH * KK + k;

    const unsigned bits = ((const unsigned*)spikes)[addr0];
    float n = series[addr0];

#pragma unroll
    for (int u = 0; u < CH; ++u) {
        const float s = (float)((bits >> u) & 1u);
        n += s;
        __builtin_nontemporal_store(s, spikes + addr0 + (size_t)u * KK);
        __builtin_nontemporal_store(n, series + addr0 + (size_t)u * KK);
    }
}

extern "C" void kernel_launch(void* const* d_in, const int* in_sizes, int n_in,
                              void* d_out, int out_size, void* d_ws, size_t ws_size,
                              hipStream_t stream) {
    const float* I = (const float*)d_in[0];
    float* spikes = (float*)d_out;
    float* series = (float*)d_out + (size_t)32 * LL * KK;
    lif_scan<<<256, 64, 0, stream>>>(I, spikes, series);
    lif_expand<<<4096, 256, 0, stream>>>(spikes, series);
}

// Round 6
// 162.784 us; speedup vs baseline: 1.0351x; 1.0206x over previous
//
#include <hip/hip_runtime.h>

// MultiLIF forward: B=32, L=2048, K=512. Serial scan over t; 256 waves
// (1 wave/CU, structural). R6: the scan is load-MLP-bound (R5 proved stores
// irrelevant: 157us with 8MB writes vs 162us with 268MB). Per-wave in-flight
// bytes were capped at 32 slots x 256B. Fix: global_load_lds width-16 DMA --
// 1 KB (4 time-rows) per vmcnt slot -- into a 40-quad LDS ring (40KB, 160-step
// depth, ~40KB in flight/wave). Hand-counted waits: vmcnt(NQ-2) min-safe for
// "quad q+1 retired" across all iterations; lgkmcnt(0) at iter top is free
// (reads issued a full iter earlier) and guards slot reuse before the DMA
// overwrites slot(q). Outputs stay packed (bits + chunk base, 8MB); proven
// expand kernel regenerates the 268MB at full occupancy.
//
// Numerics (absmax 0): x/20, x/100 via split-constant fma (single-rounding of
// x*(HI+LO), error ~2^-49 vs >=~2^-30 midpoint margin -> == IEEE division for
// all f32). th = 1 + 1.5*a as separate mul+add (contract off). Exact selects.

#define LL 2048
#define KK 512

constexpr int NQ = 40;          // LDS ring quads (4 steps each): 40 KB
constexpr int NQUADS = LL / 4;  // 512
constexpr int CH = 32;          // steps per packed chunk

constexpr float C20_HI = 0.05f;
constexpr float C20_LO = (float)(0.05 - (double)C20_HI);
constexpr float C100_HI = 0.01f;
constexpr float C100_LO = (float)(0.01 - (double)C100_HI);

__global__ __launch_bounds__(64, 1) void lif_scan(const float* __restrict__ I,
                                                  float* __restrict__ spikes,
                                                  float* __restrict__ series) {
#pragma clang fp contract(off)
    __shared__ float ring[NQ][4][64];
    const int l = threadIdx.x;
    const int e0 = blockIdx.x * 64;
    const int b = e0 >> 9;
    const int k0 = e0 & 511;
    const size_t base = (size_t)b * LL * KK;

    // per-lane DMA source: row (l>>4) of the quad, 4 floats at col 4*(l&15).
    // LDS landing = base + l*16 bytes == [4][64] row-major: exact match.
    const float* gsrc0 = I + base + (size_t)(l >> 4) * KK + (size_t)(k0 + 4 * (l & 15));
    const float* gsrc_last = gsrc0 + (size_t)(NQUADS - 1) * 4 * KK;
    const float* gsrc = gsrc0 + (size_t)NQ * 4 * KK;  // src for quad q+NQ at q=0

    const size_t cbase = base + (size_t)(k0 + l);
    float* ssp = series + cbase;
    unsigned* spp = (unsigned*)spikes + cbase;

    // prologue: fill the ring (NQ DMAs outstanding)
    {
        const float* g = gsrc0;
        for (int q = 0; q < NQ; ++q) {
            __builtin_amdgcn_global_load_lds(
                (const __attribute__((address_space(1))) void*)g,
                (__attribute__((address_space(3))) void*)&ring[q][0][0], 16, 0, 0);
            g += 4 * KK;
        }
    }
    asm volatile("s_waitcnt vmcnt(%0)" ::"n"(NQ - 1) : "memory");
    float cur[4];
#pragma unroll
    for (int j = 0; j < 4; ++j) cur[j] = ring[0][j][l];
    asm volatile("s_waitcnt lgkmcnt(0)" ::: "memory");

    float v = 0.0f, a = 0.0f, n = 0.0f;
    unsigned bits = 0;
    int slotD = 0;  // slot of quad q (freed last iter; DMA dest this iter)
    int slot1 = 1;  // slot of quad q+1 (ds_read this iter)

    for (int q = 0; q < NQUADS; ++q) {
        const int qc = q & 7;

        // quad q+1's DMA retired when <= NQ-2 newer vmcnt ops remain
        // (min over all q incl. startup; stores only cause harmless over-wait)
        asm volatile("s_waitcnt vmcnt(%0)" ::"n"(NQ - 2) : "memory");
        // drain last iter's ds_reads (issued a full iter ago: ~free) --
        // validates cur[] and guarantees slot(q) is no longer being read
        asm volatile("s_waitcnt lgkmcnt(0)" ::: "memory");

        // DMA quad q+NQ into the just-freed slot(q); src clamped at the tail
        // (dead data: slots for quads >= NQUADS are never consumed)
        {
            const float* g = (q + NQ < NQUADS) ? gsrc : gsrc_last;
            __builtin_amdgcn_global_load_lds(
                (const __attribute__((address_space(1))) void*)g,
                (__attribute__((address_space(3))) void*)&ring[slotD][0][0], 16, 0, 0);
        }

        // software-pipelined reads for quad q+1 (consumed next iter)
        float nxt[4];
#pragma unroll
        for (int j = 0; j < 4; ++j) nxt[j] = ring[slot1][j][l];

        if (qc == 0) { *ssp = n; bits = 0; }  // chunk head: count before chunk

#pragma unroll
        for (int j = 0; j < 4; ++j) {
            const float It = cur[j];
            const float d1 = __builtin_fmaf(v, C20_HI, v * C20_LO);
            v = v - d1 + It;                    // (v - v/20) + I_t
            const float th = 1.0f + 1.5f * a;   // mul then add, no fma
            const bool fired = (v >= th);
            const float s1 = fired ? 1.0f : 0.0f;
            n = n + s1;
            v = fired ? -0.5f : v;              // exact reset select
            const float d2 = __builtin_fmaf(a, C100_HI, a * C100_LO);
            a = a - d2 + s1;                    // (a - a/100) + s
            bits |= (fired ? 1u : 0u) << ((qc << 2) + j);
        }

        if (qc == 7) {
            *spp = bits;
            ssp += (size_t)CH * KK;
            spp += (size_t)CH * KK;
        }

#pragma unroll
        for (int j = 0; j < 4; ++j) cur[j] = nxt[j];
        slotD = slot1;
        slot1 = (slot1 + 1 == NQ) ? 0 : slot1 + 1;
        gsrc += 4 * KK;
    }
}

__global__ __launch_bounds__(256) void lif_expand(float* __restrict__ spikes,
                                                  float* __restrict__ series) {
    const int gid = blockIdx.x * 256 + threadIdx.x;
    const int lane = gid & 63;
    const int w = gid >> 6;            // 0..16383 = ((b*64)+c)*8 + kg
    const int kg = w & 7;
    const int c = (w >> 3) & 63;
    const int b = w >> 9;
    const int k = kg * 64 + lane;
    const size_t addr0 = (size_t)b * LL * KK + (size_t)c * CH * KK + k;

    const unsigned bits = ((const unsigned*)spikes)[addr0];
    float n = series[addr0];

#pragma unroll
    for (int u = 0; u < CH; ++u) {
        const float s = (float)((bits >> u) & 1u);
        n += s;
        __builtin_nontemporal_store(s, spikes + addr0 + (size_t)u * KK);
        __builtin_nontemporal_store(n, series + addr0 + (size_t)u * KK);
    }
}

extern "C" void kernel_launch(void* const* d_in, const int* in_sizes, int n_in,
                              void* d_out, int out_size, void* d_ws, size_t ws_size,
                              hipStream_t stream) {
    const float* I = (const float*)d_in[0];
    float* spikes = (float*)d_out;
    float* series = (float*)d_out + (size_t)32 * LL * KK;
    lif_scan<<<256, 64, 0, stream>>>(I, spikes, series);
    lif_expand<<<4096, 256, 0, stream>>>(spikes, series);
}

// Round 7
// 80.280 us; speedup vs baseline: 2.0989x; 2.0277x over previous
//
#include <hip/hip_runtime.h>

// MultiLIF forward: B=32, L=2048, K=512. Fused producer/consumer kernel.
// 256 blocks x 512 threads (8 waves/CU, 1 block/CU, 64 chains/block):
//   wave 0    : serial LIF scan, input from LDS ring only (no global ops on
//               the chain); setprio(1).
//   waves 1-2 : DMA issuers. 8x global_load_lds (1KB) per 32-step chunk into
//               an 8-chunk (64KB) LDS ring; counted s_waitcnt vmcnt(24)
//               (= 4 DMAs x (NCH-2) in flight), never drained to 0. No stores
//               on these waves so the count stays exact; tail issues clamped
//               garbage DMAs to keep the count uniform.
//   waves 3-7 : expanders. Read packed {bits, base n} from a 2-deep LDS
//               handoff and stream the 268MB f32 outputs (nt stores),
//               overlapped under the scan.
// Two raw s_barriers per window (never __syncthreads -> no vmcnt(0) drain):
//   B_A after issuer wait  : chunks <= w+1 resident in LDS
//   B_B after compute/expand: ring slot (w%8) free for the w+1 DMA;
//                             packed[w&1] visible to expanders at w+1.
//
// Numerics (absmax 0, proven R5/R6): x/20, x/100 via split-constant fma
// (single rounding of x*(HI+LO), err ~2^-49 vs >= ~2^-30 midpoint margin ->
// == IEEE division for all f32). th = 1 + 1.5*a separate mul+add (contract
// off). Spike select/reset exact; counts are small ints, exact in f32.

#define LL 2048
#define KK 512

constexpr int NCH = 8;        // ring depth (chunks)
constexpr int CH = 32;        // steps per chunk
constexpr int NWIN = LL / CH; // 64

constexpr float C20_HI = 0.05f;
constexpr float C20_LO = (float)(0.05 - (double)C20_HI);
constexpr float C100_HI = 0.01f;
constexpr float C100_LO = (float)(0.01 - (double)C100_HI);

__global__ __launch_bounds__(512, 1) void lif_fused(const float* __restrict__ I,
                                                    float* __restrict__ spikes,
                                                    float* __restrict__ series) {
#pragma clang fp contract(off)
    __shared__ float ring[NCH][CH][64];   // 64 KB
    __shared__ unsigned pbits[2][64];     // packed spikes handoff
    __shared__ float pbase[2][64];        // chunk-base running count

    const int tid = threadIdx.x;
    const int wid = tid >> 6;
    const int l = tid & 63;
    const int e0 = blockIdx.x * 64;       // first chain of this block
    const int b = e0 >> 9;
    const int k0 = e0 & 511;
    const size_t base = (size_t)b * LL * KK;

    if (wid == 1 || wid == 2) {
        // ---------------- DMA issuers ----------------
        const int j0 = (wid - 1) * 4;     // DMA quads j0..j0+3 of each chunk
        // lane source for DMA j of chunk c:
        //   I + base + (c*CH + 4j + (l>>4))*KK + k0 + 4*(l&15)
        // LDS landing = dest + l*16B == [4][64] row-major: exact match.
        const float* g0 = I + base + (size_t)(l >> 4) * KK + (k0 + 4 * (l & 15));

        // prologue: chunks 0..NCH-2
        for (int c = 0; c < NCH - 1; ++c) {
#pragma unroll
            for (int jj = 0; jj < 4; ++jj) {
                const int j = j0 + jj;
                const float* g = g0 + (size_t)(c * CH + 4 * j) * KK;
                __builtin_amdgcn_global_load_lds(
                    (const __attribute__((address_space(1))) void*)g,
                    (__attribute__((address_space(3))) void*)&ring[c][4 * j][0],
                    16, 0, 0);
            }
        }
        for (int w = 0; w <= NWIN; ++w) {
            int c = w + NCH - 1;
            if (c > NWIN - 1) c = NWIN - 1;            // tail: clamped garbage
            const int slot = (w + NCH - 1) & (NCH - 1); // == (w-1)%8: freed at B_B(w-1)
#pragma unroll
            for (int jj = 0; jj < 4; ++jj) {
                const int j = j0 + jj;
                const float* g = g0 + (size_t)(c * CH + 4 * j) * KK;
                __builtin_amdgcn_global_load_lds(
                    (const __attribute__((address_space(1))) void*)g,
                    (__attribute__((address_space(3))) void*)&ring[slot][4 * j][0],
                    16, 0, 0);
            }
            // 7 chunks x4 outstanding -> keep 6 chunks (24): chunk w+1 landed
            asm volatile("s_waitcnt vmcnt(24)" ::: "memory");
            asm volatile("s_barrier" ::: "memory");    // B_A
            asm volatile("s_barrier" ::: "memory");    // B_B
        }
    } else if (wid == 0) {
        // ---------------- consumer: serial scan ----------------
        __builtin_amdgcn_s_setprio(1);
        float v = 0.0f, a = 0.0f, n = 0.0f;
        for (int w = 0; w <= NWIN; ++w) {
            asm volatile("s_barrier" ::: "memory");    // B_A: chunk w resident
            if (w < NWIN) {
                const int slot = w & (NCH - 1);
                pbase[w & 1][l] = n;                   // count BEFORE chunk
                unsigned bits = 0;
                float cur[4], nxt[4];
#pragma unroll
                for (int i = 0; i < 4; ++i) cur[i] = ring[slot][i][l];
#pragma unroll
                for (int q = 0; q < 8; ++q) {
                    if (q < 7) {
#pragma unroll
                        for (int i = 0; i < 4; ++i)
                            nxt[i] = ring[slot][4 * q + 4 + i][l];
                    }
#pragma unroll
                    for (int i = 0; i < 4; ++i) {
                        const float It = cur[i];
                        const float d1 = __builtin_fmaf(v, C20_HI, v * C20_LO);
                        v = v - d1 + It;               // (v - v/20) + I_t
                        const float th = 1.0f + 1.5f * a;
                        const bool fired = (v >= th);
                        const float s1 = fired ? 1.0f : 0.0f;
                        n = n + s1;
                        v = fired ? -0.5f : v;         // exact reset select
                        const float d2 = __builtin_fmaf(a, C100_HI, a * C100_LO);
                        a = a - d2 + s1;               // (a - a/100) + s
                        bits |= (fired ? 1u : 0u) << (4 * q + i);
                    }
#pragma unroll
                    for (int i = 0; i < 4; ++i) cur[i] = nxt[i];
                }
                pbits[w & 1][l] = bits;
            }
            // drain ds ops: packed visible + done reading ring slot w%8
            asm volatile("s_waitcnt lgkmcnt(0)" ::: "memory");
            asm volatile("s_barrier" ::: "memory");    // B_B
        }
    } else {
        // ---------------- expanders (wid 3..7) ----------------
        const int xi = wid - 3;                        // 0..4
        const int t0 = (xi < 2) ? xi * 7 : 14 + (xi - 2) * 6;
        const int t1 = (xi < 2) ? t0 + 7 : t0 + 6;     // slices 7,7,6,6,6
        float* spb = spikes + base + (k0 + l);
        float* ssb = series + base + (k0 + l);
        for (int w = 0; w <= NWIN; ++w) {
            asm volatile("s_barrier" ::: "memory");    // B_A
            if (w >= 1) {
                const int c = w - 1;
                const unsigned bits = pbits[c & 1][l];
                float nr = pbase[c & 1][l] +
                           (float)__popc(bits & ((1u << t0) - 1u));
                for (int t = t0; t < t1; ++t) {
                    const float s1 = (float)((bits >> t) & 1u);
                    nr += s1;
                    const size_t off = (size_t)(c * CH + t) * KK;
                    __builtin_nontemporal_store(s1, spb + off);
                    __builtin_nontemporal_store(nr, ssb + off);
                }
            }
            asm volatile("s_barrier" ::: "memory");    // B_B
        }
    }
}

extern "C" void kernel_launch(void* const* d_in, const int* in_sizes, int n_in,
                              void* d_out, int out_size, void* d_ws, size_t ws_size,
                              hipStream_t stream) {
    const float* I = (const float*)d_in[0];
    float* spikes = (float*)d_out;
    float* series = (float*)d_out + (size_t)32 * LL * KK;
    lif_fused<<<256, 512, 0, stream>>>(I, spikes, series);
}